// Round 10
// baseline (177.764 us; speedup 1.0000x reference)
//
#include <hip/hip_runtime.h>
#include <hip/hip_bf16.h>

// Problem geometry
#define N_ROWS 32000   // Q_OUT*Q_IN*NUM_P
#define SB     12      // SCALAR_BASIS
#define FC     720     // FILTER_C
#define FD     2704    // FILTER_DIM
#define OCOLS  2704    // DIM_OUT*DIM_IN
#define OPAD   2816    // OCOLS padded to 22*128
#define ANGD   25
#define PDIM   300     // SB * ANGD
#define KST    320     // PDIM padded to 5*64
#define NT     5       // K tiles of 64

typedef __attribute__((ext_vector_type(8))) short bf16x8;
typedef __attribute__((ext_vector_type(4))) float f32x4;

__device__ __forceinline__ void gload16(const void* g, void* l) {
    __builtin_amdgcn_global_load_lds(
        (const __attribute__((address_space(1))) void*)g,
        (__attribute__((address_space(3))) void*)l, 16, 0, 0);
}

// ---------------------------------------------------------------------------
// Kernel A v2: V[o, s*25+alpha] = sum_c TP[o, ...] * (W[s, ...]/sqrt(12)).
// 320 threads: one p per thread. 4 independent accumulators (ILP).
// ---------------------------------------------------------------------------
__global__ __launch_bounds__(320) void build_V(
    const float* __restrict__ TP,
    const float* __restrict__ W,
    __hip_bfloat16* __restrict__ V)
{
    const int o   = blockIdx.x;   // 0..OPAD-1
    const int tid = threadIdx.x;  // 0..319
    __shared__ float s_tp[FD];        // 10816 B
    __shared__ float s_w[SB * FC];    // 34560 B

    const float inv = 0.28867513459481288f; // 1/sqrt(12)
    for (int i = tid; i < SB * FC; i += 320) s_w[i] = W[i] * inv;
    if (o < OCOLS) {
        for (int i = tid; i < FD; i += 320) s_tp[i] = TP[(size_t)o * FD + i];
    } else {
        for (int i = tid; i < FD; i += 320) s_tp[i] = 0.f;
    }
    __syncthreads();

    const int p = tid;   // one p per thread
    float acc = 0.f;
    if (p < PDIM) {
        const int s     = p / ANGD;
        const int alpha = p - s * ANGD;
        int m, off, sco, al, Cl;
        if (alpha < 1)       { m = 1; off = 0;    sco = 0;   al = 0;  Cl = 144; }
        else if (alpha < 4)  { m = 3; off = 144;  sco = 144; al = 1;  Cl = 272; }
        else if (alpha < 9)  { m = 5; off = 960;  sco = 416; al = 4;  Cl = 208; }
        else if (alpha < 16) { m = 7; off = 2000; sco = 624; al = 9;  Cl = 80;  }
        else                 { m = 9; off = 2560; sco = 704; al = 16; Cl = 16;  }
        const int j = alpha - al;
        const float* tp = s_tp + off + j;
        const float* ww = s_w + s * FC + sco;
        float a0 = 0.f, a1 = 0.f, a2 = 0.f, a3 = 0.f;
        for (int c = 0; c < Cl; c += 4) {
            a0 += tp[(c + 0) * m] * ww[c + 0];
            a1 += tp[(c + 1) * m] * ww[c + 1];
            a2 += tp[(c + 2) * m] * ww[c + 2];
            a3 += tp[(c + 3) * m] * ww[c + 3];
        }
        acc = (a0 + a1) + (a2 + a3);
    }
    if (p < KST) V[(size_t)o * KST + p] = __float2bfloat16(acc);
}

// ---------------------------------------------------------------------------
// Kernel B: X[n, s*25+alpha] = sk[n,s] * ang[n,alpha], bf16, padded to KST.
// ---------------------------------------------------------------------------
__global__ void build_X(const float* __restrict__ sk,
                        const float* __restrict__ ang,
                        __hip_bfloat16* __restrict__ X)
{
    const int idx = blockIdx.x * 256 + threadIdx.x;
    if (idx >= N_ROWS * (KST / 8)) return;
    const int n  = idx / (KST / 8);
    const int p0 = (idx - n * (KST / 8)) * 8;
    const float* skn  = sk  + (size_t)n * SB;
    const float* angn = ang + (size_t)n * ANGD;
    alignas(16) __hip_bfloat16 tmp[8];
    #pragma unroll
    for (int u = 0; u < 8; ++u) {
        const int p = p0 + u;
        float v = 0.f;
        if (p < PDIM) {
            const int s = p / ANGD;
            const int a = p - s * ANGD;
            v = skn[s] * angn[a];
        }
        tmp[u] = __float2bfloat16(v);
    }
    *(bf16x8*)(X + (size_t)n * KST + p0) = *(const bf16x8*)tmp;
}

// ---------------------------------------------------------------------------
// Kernel C: 128x128-tile bf16 GEMM, write-bound K=320 regime.
// Inner loop identical to rounds 7-9. Epilogue: LDS-routed full-line
// stores, now NORMAL (not nontemporal) — fill-kernel evidence shows the
// normal path does 6.8 TB/s of writes; nt was capping us near ~3 TB/s.
// Full 1 KB/wave contiguous stores avoid write-allocate RMW anyway.
// ---------------------------------------------------------------------------
__global__ __launch_bounds__(512, 4) void gemm_bt(
    const __hip_bfloat16* __restrict__ A,   // X: (N_ROWS, KST)
    const __hip_bfloat16* __restrict__ B,   // V: (OPAD, KST)
    float* __restrict__ C)
{
    __shared__ __align__(1024) char lds[65536];
    char* const bufA = lds;            // 2 x 16384 B
    char* const bufB = lds + 32768;    // 2 x 16384 B
    float* const s_c = (float*)lds;    // epilogue alias: [64][132] f32

    const int tid  = threadIdx.x;
    const int wave = tid >> 6;
    const int lane = tid & 63;

    const int bn = blockIdx.x;         // 22 col tiles
    const int bm = blockIdx.y;         // 250 row tiles
    const size_t arow0 = (size_t)bm * 128;
    const size_t brow0 = (size_t)bn * 128;

    const int wr = wave >> 2;   // 0..1 (M half: 64 rows)
    const int wc = wave & 3;    // 0..3 (N quarter: 32 cols)

    // staging lane constants (LDS linear dest; global source pre-swizzled)
    const int lrow  = lane >> 3;
    const int lslot = ((lane & 7) ^ (lrow & 7)) << 4;

    auto STAGE = [&](const char* gbase, size_t growbase, int t, char* lbase) {
        const char* g0 = gbase + (growbase + (size_t)(wave * 8 + lrow)) * (KST * 2)
                               + (size_t)t * 128 + lslot;
        gload16(g0,                          lbase + wave * 1024);
        gload16(g0 + (size_t)64 * (KST * 2), lbase + 8192 + wave * 1024);
    };

    // reader lane constants (swizzle: slot = (ks*4+koct) ^ (row&7))
    const int rl   = lane & 15;
    const int koct = lane >> 4;
    const int sK0 = ((0 * 4 + koct) ^ (lane & 7)) << 4;
    const int sK1 = ((1 * 4 + koct) ^ (lane & 7)) << 4;

    // prologue: stage t0 into buf0, t1 into buf1
    STAGE((const char*)A, arow0, 0, bufA + 0);
    STAGE((const char*)B, brow0, 0, bufB + 0);
    STAGE((const char*)A, arow0, 1, bufA + 16384);
    STAGE((const char*)B, brow0, 1, bufB + 16384);
    asm volatile("s_waitcnt vmcnt(4)" ::: "memory");
    __builtin_amdgcn_s_barrier();

    f32x4 acc[4][2] = {};   // [m][n]; D^T frags: row=o, col=M

    for (int t = 0; t < NT; ++t) {
        char* const aC = bufA + (t & 1) * 16384;
        char* const bC = bufB + (t & 1) * 16384;

        bf16x8 af[4][2], bfr[2][2];
        #pragma unroll
        for (int m = 0; m < 4; ++m) {
            const int r = wr * 64 + m * 16 + rl;
            af[m][0] = *(const bf16x8*)(aC + r * 128 + sK0);
            af[m][1] = *(const bf16x8*)(aC + r * 128 + sK1);
        }
        #pragma unroll
        for (int n = 0; n < 2; ++n) {
            const int r = wc * 32 + n * 16 + rl;
            bfr[n][0] = *(const bf16x8*)(bC + r * 128 + sK0);
            bfr[n][1] = *(const bf16x8*)(bC + r * 128 + sK1);
        }
        asm volatile("s_waitcnt lgkmcnt(0)" ::: "memory");
        __builtin_amdgcn_sched_barrier(0);
        __builtin_amdgcn_s_barrier();   // all waves done reading this buf

        if (t + 2 < NT) {               // stage t+2 into the buffer just read
            STAGE((const char*)A, arow0, t + 2, aC);
            STAGE((const char*)B, brow0, t + 2, bC);
        }

        __builtin_amdgcn_s_setprio(1);
        #pragma unroll
        for (int ks = 0; ks < 2; ++ks)
            #pragma unroll
            for (int m = 0; m < 4; ++m)
                #pragma unroll
                for (int n = 0; n < 2; ++n)
                    acc[m][n] = __builtin_amdgcn_mfma_f32_16x16x32_bf16(
                        bfr[n][ks], af[m][ks], acc[m][n], 0, 0, 0);
        __builtin_amdgcn_s_setprio(0);
        __builtin_amdgcn_sched_barrier(0);

        if (t < NT - 2)       asm volatile("s_waitcnt vmcnt(4)" ::: "memory");
        else if (t == NT - 2) asm volatile("s_waitcnt vmcnt(0)" ::: "memory");
        if (t < NT - 1) __builtin_amdgcn_s_barrier();
    }

    // ---- epilogue through LDS: two 64-row passes, full-line stores ----
    // acc[m][n] = 4 consecutive o at fixed M:
    //   M = arow0 + wr*64 + m*16 + rl,  o = brow0 + wc*32 + n*16 + koct*4
    #pragma unroll
    for (int h = 0; h < 2; ++h) {
        __syncthreads();   // previous pass reads (or K-loop LDS reads) done
        if (wr == h) {
            #pragma unroll
            for (int m = 0; m < 4; ++m) {
                const int row_l = m * 16 + rl;             // 0..63
                #pragma unroll
                for (int n = 0; n < 2; ++n) {
                    const int col = wc * 32 + n * 16 + koct * 4;   // 0..124
                    *(f32x4*)&s_c[row_l * 132 + col] = acc[m][n];
                }
            }
        }
        __syncthreads();
        // read back linearly: 64 rows x 32 f32x4-groups = 2048 groups
        #pragma unroll
        for (int rr = 0; rr < 4; ++rr) {
            const int idx  = rr * 512 + tid;
            const int row  = idx >> 5;
            const int g4   = (idx & 31) * 4;
            if ((int)brow0 + g4 < OCOLS) {
                const f32x4 v = *(const f32x4*)&s_c[row * 132 + g4];
                *(f32x4*)(C + (size_t)(arow0 + h * 64 + row) * OCOLS + brow0 + g4) = v;
            }
        }
    }
}

// ---------------------------------------------------------------------------
extern "C" void kernel_launch(void* const* d_in, const int* in_sizes, int n_in,
                              void* d_out, int out_size, void* d_ws, size_t ws_size,
                              hipStream_t stream)
{
    const float* sk  = (const float*)d_in[0];   // (16,16,125,12)
    const float* ang = (const float*)d_in[1];   // (32000,25)
    const float* W   = (const float*)d_in[2];   // (12,720)
    const float* TP  = (const float*)d_in[3];   // (2704,2704)
    float* out = (float*)d_out;                 // (32000,2704)

    __hip_bfloat16* X  = (__hip_bfloat16*)d_ws;             // N_ROWS*KST bf16 (20.5 MB)
    __hip_bfloat16* Vb = X + (size_t)N_ROWS * KST;          // OPAD*KST bf16 (1.8 MB)

    build_V<<<OPAD, 320, 0, stream>>>(TP, W, Vb);
    build_X<<<(N_ROWS * (KST / 8) + 255) / 256, 256, 0, stream>>>(sk, ang, X);

    dim3 grid(OPAD / 128, N_ROWS / 128);   // (22, 250)
    gemm_bt<<<grid, 512, 0, stream>>>(X, Vb, out);
}